// Round 8
// baseline (552.735 us; speedup 1.0000x reference)
//
#include <hip/hip_runtime.h>

#define NN 100000
#define NE 1600000
#define WT 12
#define CI 16
#define CM 32
#define CO 32

#define NCHUNK 392           // ceil(NN/256)+pad so 12*NCHUNK %8==0
#define NND (NCHUNK * 256)   // padded nodes per t-plane (100352)

#define FXS 33554432.0f   // 2^25 fixed-point scale for deg

// ---- bf16 pack (round-to-nearest-even), 2 channels per uint ---------------
__device__ __forceinline__ unsigned bf16pack(float a, float b) {
    unsigned ua = __float_as_uint(a);
    unsigned ub = __float_as_uint(b);
    ua = (ua + 0x7FFFu + ((ua >> 16) & 1u)) >> 16;
    ub = (ub + 0x7FFFu + ((ub >> 16) & 1u)) >> 16;
    return ua | (ub << 16);
}

// ---------------- K0: transpose x [t][n][ci] -> xTb [n][96 uints] ----------
__global__ void k_xpose(const float* __restrict__ x, unsigned* __restrict__ xTb) {
    int f = blockIdx.x * 256 + threadIdx.x;            // over NN*96
    if (f >= NN * 96) return;
    int n = f / 96;
    int u = f - n * 96;
    int t = u >> 3;
    int p = u & 7;
    const float2* x2 = (const float2*)x;
    float2 v = x2[((size_t)t * NN + n) * 8 + p];
    xTb[f] = bf16pack(v.x, v.y);
}

// ---------------- K1: ONE packed 64-bit atomic per edge --------------------
// pk[c] bits 40+: count; bits 0..39: fixed-point weighted degree (ew * 2^25).
// Returned old value gives this edge's rank within its destination.
__global__ void k_count(const int* __restrict__ A, const float* __restrict__ ew,
                        unsigned long long* __restrict__ pk, int* __restrict__ rank) {
    int e = blockIdx.x * 256 + threadIdx.x;
    if (e >= NE) return;
    int c = A[NE + e];
    unsigned long long fx = (unsigned long long)(ew[e] * FXS + 0.5f);
    unsigned long long old = atomicAdd(&pk[c], (1ull << 40) | fx);
    rank[e] = (int)(old >> 40);
}

// ---------------- K2: dis = rsqrt(deg), segment allocation (wave-scan) -----
// ds[n] = {start, cnt}; dis[n] = deg>0 ? rsqrt(deg) : 0
__global__ void k_dis_alloc(const unsigned long long* __restrict__ pk,
                            float* __restrict__ dis, int2* __restrict__ ds,
                            int* __restrict__ total) {
    int n = blockIdx.x * 256 + threadIdx.x;
    bool valid = (n < NN);
    int c = 0;
    if (valid) {
        unsigned long long v = pk[n];
        c = (int)(v >> 40);
        float d = (float)(v & ((1ull << 40) - 1)) * (1.0f / FXS);
        dis[n] = d > 0.0f ? rsqrtf(d) : 0.0f;
    }
    int lane = threadIdx.x & 63;
    int inc = c;
    #pragma unroll
    for (int o = 1; o < 64; o <<= 1) {
        int v = __shfl_up(inc, o, 64);
        if (lane >= o) inc += v;
    }
    int base = 0;
    if (lane == 63) base = atomicAdd(total, inc);   // one atomic per wave
    base = __shfl(base, 63, 64);
    if (valid) ds[n] = make_int2(base + inc - c, c);
}

// ---------------- K3: atomic-free scatter ----------------------------------
// meta[p] = {src, dis[src]*ew}; dis[dst] applied at end of k_agg instead.
__global__ void k_scatter(const int* __restrict__ A, const float* __restrict__ ew,
                          const float* __restrict__ dis, const int2* __restrict__ ds,
                          const int* __restrict__ rank, float2* __restrict__ meta) {
    int e = blockIdx.x * 256 + threadIdx.x;
    if (e >= NE) return;
    int r = A[e];
    int c = A[NE + e];
    float w = dis[r] * ew[e];
    int p = ds[c].x + rank[e];
    meta[p] = make_float2(__int_as_float(r), w);
}

// ---------------- K4: aggregation, one wave per dst node -------------------
// Lane l<48 loads uint2 -> whole 384B bf16 row in ONE coalesced dwordx2.
// 4 fp32 accs/lane (flat channels 4l..4l+3); dis[node] applied once at end.
// xagg is now T-MAJOR: [12 planes][NND nodes][16 floats]. Lane l holds
// flat channels 4l..4l+3 = plane l>>2, float4-quad l&3 of its node row.
__global__ __launch_bounds__(256) void k_agg(const unsigned* __restrict__ xTb,
                      const int2* __restrict__ ds, const float* __restrict__ dis,
                      const float2* __restrict__ meta, float* __restrict__ xagg) {
    int wave = threadIdx.x >> 6;
    int lane = threadIdx.x & 63;
    int node = blockIdx.x * 4 + wave;
    int2 sc = ds[node];
    int s = __builtin_amdgcn_readfirstlane(sc.x);   // force scalar -> s_load meta
    int c = __builtin_amdgcn_readfirstlane(sc.y);
    int li = lane < 48 ? lane : 47;                 // clamp: same cache line, no branch
    float4 acc = make_float4(0.f, 0.f, 0.f, 0.f);
    const float2* mp = meta + s;
    #pragma unroll 4
    for (int i = 0; i < c; i++) {
        float2 m = mp[i];                           // wave-uniform -> scalar load
        int src = __float_as_int(m.x);
        float w = m.y;
        uint2 u = ((const uint2*)(xTb + (size_t)src * 96))[li];
        acc.x += w * __uint_as_float(u.x << 16);
        acc.y += w * __uint_as_float(u.x & 0xFFFF0000u);
        acc.z += w * __uint_as_float(u.y << 16);
        acc.w += w * __uint_as_float(u.y & 0xFFFF0000u);
    }
    float dn = dis[node];
    acc.x *= dn; acc.y *= dn; acc.z *= dn; acc.w *= dn;
    if (lane < 48)
        ((float4*)xagg)[(size_t)(lane >> 2) * (NND * 4) + node * 4 + (lane & 3)] = acc;
}

// ---------------- K5a: fold GCN weight into conv weight --------------------
__global__ void k_foldW(const float* __restrict__ gw, const float* __restrict__ cw,
                        float* __restrict__ M2) {
    int i = blockIdx.x * 256 + threadIdx.x;
    if (i >= WT * 3 * CI * CO) return;
    int co = i & 31;
    int rem = i >> 5;            // t*48 + k*16 + ci
    int ci = rem & 15;
    int kidx = rem % 48;
    int k = kidx >> 4;
    int t = rem / 48;
    int tp = t + k - 1;
    float s = 0.0f;
    if (tp >= 0 && tp < WT) {
        for (int cm = 0; cm < CM; cm++)
            s += gw[(tp * CI + ci) * CM + cm] * cw[co * (CM * 3) + cm * 3 + k];
    }
    M2[i] = s;
}

// ---------------- K5b: fold biases -----------------------------------------
__global__ void k_foldB(const float* __restrict__ gb, const float* __restrict__ cw,
                        const float* __restrict__ cb, float* __restrict__ B2) {
    int i = blockIdx.x * 256 + threadIdx.x;
    if (i >= WT * CO) return;
    int co = i & 31;
    int t = i >> 5;
    float s = cb[co];
    for (int k = 0; k < 3; k++) {
        int tp = t + k - 1;
        if (tp < 0 || tp >= WT) continue;
        for (int cm = 0; cm < CM; cm++)
            s += gb[tp * CM + cm] * cw[co * (CM * 3) + cm * 3 + k];
    }
    B2[i] = s;
}

// ---------------- K7: per-(chunk,t), t-major xagg + LDS coop staging -------
// Grid = 392 chunks x 12 t = 4704 blocks (%8==0), XCD-swizzled so the 12
// t-sharers of a chunk run back-to-back on ONE XCD (L2-resident re-reads).
// ROUND-7 DIAGNOSIS: node-major xagg rows (768B) made every dwordx4 load
// lane-stride 768B -> 64 cache lines PER INSTRUCTION, 768 line-touches per
// wave for ~12KB -> ~6x L1<->L2 transaction amplification; two different
// k_out structures both pinned at ~103us with VALU 27%, HBM 23%.
// FIX: xagg is t-major [12][NND][16]; the block's 3 planes are 16KB
// CONTIGUOUS each -> 256 threads stage them into LDS with fully-dense
// float4 loads (8 lines/instr, 96 touches/wave = compulsory min). LDS rows
// padded to 80B so the per-thread b128 reads are ~8-way (2.9x, ~420cyc,
// acceptable). Weight panel stays s_load (t block-uniform). Stores plain
// (full 128B line per thread; L2 merges -> WRITE stays ~153MB).
__global__ __launch_bounds__(256) void k_out(const float* __restrict__ xagg,
                                             const float* __restrict__ M2,
                                             const float* __restrict__ B2,
                                             float* __restrict__ out) {
    int wgid  = ((int)blockIdx.x & 7) * 588 + ((int)blockIdx.x >> 3);
    int chunk = wgid / 12;
    int t     = wgid - chunk * 12;               // block-uniform -> s_load
    int tid   = (int)threadIdx.x;
    int n     = chunk * 256 + tid;

    __shared__ float lds[3 * 5120];              // 3 planes x 256 rows x 80B

    // cooperative stage: 3 planes x 1024 float4, fully coalesced
    #pragma unroll
    for (int p = 0; p < 3; p++) {
        int tp = t + p - 1;                      // block-uniform branch
        float* ldsp = lds + p * 5120;
        if (tp >= 0 && tp < WT) {
            const float4* gp = (const float4*)xagg + (size_t)tp * (NND * 4) + chunk * 1024;
            #pragma unroll
            for (int i = 0; i < 4; i++) {
                int idx = i * 256 + tid;
                float4 v = gp[idx];
                *(float4*)(ldsp + (idx >> 2) * 20 + (idx & 3) * 4) = v;
            }
        } else {
            #pragma unroll
            for (int i = 0; i < 4; i++) {
                int idx = i * 256 + tid;
                *(float4*)(ldsp + (idx >> 2) * 20 + (idx & 3) * 4) =
                    make_float4(0.f, 0.f, 0.f, 0.f);
            }
        }
    }
    __syncthreads();

    const float* Wt = M2 + (size_t)t * 48 * CO;  // uniform -> s_load
    float acc[CO];
    #pragma unroll
    for (int co = 0; co < CO; co++) acc[co] = B2[t * CO + co];

    #pragma unroll
    for (int p = 0; p < 3; p++) {
        #pragma unroll
        for (int q = 0; q < 4; q++) {
            float4 v = *(float4*)(lds + p * 5120 + tid * 20 + q * 4);
            float vj[4] = {v.x, v.y, v.z, v.w};
            #pragma unroll
            for (int jj = 0; jj < 4; jj++) {
                float a = vj[jj];
                const float* wrow = Wt + ((p * 16 + q * 4 + jj) * CO);
                #pragma unroll
                for (int co = 0; co < CO; co++)
                    acc[co] += a * wrow[co];
            }
        }
    }

    if (n < NN) {
        float* o = out + ((size_t)n * WT + t) * CO;
        #pragma unroll
        for (int co = 0; co < CO; co += 4) {
            float4 v;
            v.x = acc[co]     >= 0.0f ? acc[co]     : 0.01f * acc[co];
            v.y = acc[co + 1] >= 0.0f ? acc[co + 1] : 0.01f * acc[co + 1];
            v.z = acc[co + 2] >= 0.0f ? acc[co + 2] : 0.01f * acc[co + 2];
            v.w = acc[co + 3] >= 0.0f ? acc[co + 3] : 0.01f * acc[co + 3];
            *(float4*)(o + co) = v;
        }
    }
}

// ---------------- launch ----------------------------------------------------
extern "C" void kernel_launch(void* const* d_in, const int* in_sizes, int n_in,
                              void* d_out, int out_size, void* d_ws, size_t ws_size,
                              hipStream_t stream) {
    const float* x  = (const float*)d_in[0];
    const int*   A  = (const int*)d_in[1];
    const float* ew = (const float*)d_in[2];
    const float* gw = (const float*)d_in[3];
    const float* gb = (const float*)d_in[4];
    const float* cw = (const float*)d_in[5];
    const float* cb = (const float*)d_in[6];
    float* out = (float*)d_out;
    float* ws  = (float*)d_ws;

    // ws layout (float offsets), every segment a multiple of 32 floats:
    // [pk 2N (u64)][total 32][rank E][dis N][ds 2N (int2)]
    // [meta 2E (float2)][xTb N*96 (uint)][M2 18432][B2 384]
    // [xagg 12*NND*16 (t-major planes, padded to NND nodes)]
    unsigned long long* pk = (unsigned long long*)ws;
    int*      total = (int*)(ws + 2 * NN);
    int*      rank  = (int*)(ws + 2 * NN + 32);
    float*    dis   = ws + 2 * NN + 32 + NE;
    int2*     ds    = (int2*)(ws + 3 * NN + 32 + NE);
    float2*   meta  = (float2*)(ws + 5 * NN + 32 + NE);
    unsigned* xTb   = (unsigned*)(ws + 5 * NN + 32 + 3 * NE);
    float*    M2    = ws + 5 * NN + 32 + 3 * NE + NN * 96;
    float*    B2    = M2 + WT * 3 * CI * CO;
    float*    xagg  = B2 + WT * CO;

    // zero pk + total
    hipMemsetAsync(d_ws, 0, (size_t)(2 * NN + 32) * sizeof(float), stream);

    k_xpose    <<<(NN * 96) / 256, 256, 0, stream>>>(x, xTb);
    k_count    <<<(NE + 255) / 256, 256, 0, stream>>>(A, ew, pk, rank);
    k_dis_alloc<<<(NN + 255) / 256, 256, 0, stream>>>(pk, dis, ds, total);
    k_scatter  <<<(NE + 255) / 256, 256, 0, stream>>>(A, ew, dis, ds, rank, meta);
    k_agg      <<<NN / 4, 256, 0, stream>>>(xTb, ds, dis, meta, xagg);
    k_foldW    <<<(WT * 3 * CI * CO + 255) / 256, 256, 0, stream>>>(gw, cw, M2);
    k_foldB    <<<(WT * CO + 255) / 256, 256, 0, stream>>>(gb, cw, cb, B2);
    // 392 chunks (incl. pad chunk) x 12 t, %8==0 for the XCD swizzle
    k_out      <<<12 * NCHUNK, 256, 0, stream>>>(xagg, M2, B2, out);
}